// Round 1
// baseline (645.943 us; speedup 1.0000x reference)
//
#include <hip/hip_runtime.h>
#include <cmath>

#define CDIM 384
#define NB 8
#define NPIX 1024
#define NHEADS 8
#define HD 48

// ---------------------------------------------------------------------------
// Kernel 1: spectral filter.  per (b,c) 32x32 image:
//   Xf = rfft2(X, ortho); Y = Xf * Wc; y = irfft2(Y, ortho)
// implemented as explicit DFT stages (all twiddles are multiples of 2*pi/32).
// Writes y to xr (B,C,1024) and to out (B,1024,C)  [x_fft residual base].
// ---------------------------------------------------------------------------
__global__ __launch_bounds__(256) void fft_filter_k(
    const float* __restrict__ x, const float* __restrict__ cw,
    float* __restrict__ xr, float* __restrict__ out)
{
  const int b = blockIdx.x / CDIM;
  const int c = blockIdx.x % CDIM;
  const int tid = threadIdx.x;
  __shared__ float ct[32], st[32];
  __shared__ float xs[1024];
  __shared__ float t1r[1024], t1i[1024];
  __shared__ float yr2[32][17], yi2[32][17];
  __shared__ float zr2[32][18], zi2[32][18];
  if (tid < 32) {
    float ang = (float)tid * 0.19634954084936207f;  // 2*pi/32
    ct[tid] = cosf(ang);
    st[tid] = sinf(ang);
  }
  for (int i = tid; i < 1024; i += 256)
    xs[i] = x[(b * 1024 + i) * CDIM + c];
  __syncthreads();
  // stage 1: T1[u,w] = sum_h X[h,w] e^{-2pi i u h/32}
  for (int i = tid; i < 1024; i += 256) {
    int u = i >> 5, w = i & 31;
    float ar = 0.f, ai = 0.f;
#pragma unroll
    for (int h = 0; h < 32; ++h) {
      int idx = (u * h) & 31;
      float xv = xs[(h << 5) | w];
      ar += xv * ct[idx];
      ai -= xv * st[idx];
    }
    t1r[i] = ar; t1i[i] = ai;
  }
  __syncthreads();
  // stage 2: Xf[u,v] = sum_w T1[u,w] e^{-2pi i v w/32};  Y = Xf * Wc
  for (int i = tid; i < 544; i += 256) {
    int u = i / 17, v = i % 17;
    float fr = 0.f, fi = 0.f;
#pragma unroll
    for (int w = 0; w < 32; ++w) {
      int idx = (v * w) & 31;
      float tr = t1r[(u << 5) | w], ti = t1i[(u << 5) | w];
      fr += tr * ct[idx] + ti * st[idx];
      fi += ti * ct[idx] - tr * st[idx];
    }
    float wr = cw[((c * 32 + u) * 17 + v) * 2 + 0];
    float wi = cw[((c * 32 + u) * 17 + v) * 2 + 1];
    yr2[u][v] = fr * wr - fi * wi;
    yi2[u][v] = fr * wi + fi * wr;
  }
  __syncthreads();
  // stage 3: Z1[h,v] = sum_u Y[u,v] e^{+2pi i u h/32}   (ifft along u first,
  // matching numpy irfft2 order)
  for (int i = tid; i < 544; i += 256) {
    int h = i / 17, v = i % 17;
    float zr = 0.f, zi = 0.f;
#pragma unroll
    for (int u = 0; u < 32; ++u) {
      int idx = (u * h) & 31;
      float a = yr2[u][v], bb = yi2[u][v];
      zr += a * ct[idx] - bb * st[idx];
      zi += a * st[idx] + bb * ct[idx];
    }
    zr2[h][v] = zr; zi2[h][v] = zi;
  }
  __syncthreads();
  // stage 4: c2r along v (imag of v=0 and v=16 ignored, like pocketfft/XLA)
  for (int i = tid; i < 1024; i += 256) {
    int h = i >> 5, w = i & 31;
    float acc = zr2[h][0] + ((w & 1) ? -zr2[h][16] : zr2[h][16]);
#pragma unroll
    for (int v = 1; v < 16; ++v) {
      int idx = (v * w) & 31;
      acc += 2.f * (zr2[h][v] * ct[idx] - zi2[h][v] * st[idx]);
    }
    float y = acc * (1.0f / 1024.0f);  // ortho fwd (1/32) * ortho inv (1/32)
    xr[(b * CDIM + c) * 1024 + i] = y;
    out[(b * 1024 + i) * CDIM + c] = y;
  }
}

// ---------------------------------------------------------------------------
// Kernel 2: depthwise 3x3 conv (pad 1, correlation) + inference BN, for q/k/v.
// ---------------------------------------------------------------------------
__global__ __launch_bounds__(256) void conv_bn_k(
    const float* __restrict__ xr,
    const float* __restrict__ dwq, const float* __restrict__ dwk, const float* __restrict__ dwv,
    const float* __restrict__ gq, const float* __restrict__ bq, const float* __restrict__ mq, const float* __restrict__ vq,
    const float* __restrict__ gk, const float* __restrict__ bk, const float* __restrict__ mk, const float* __restrict__ vk,
    const float* __restrict__ gv, const float* __restrict__ bv, const float* __restrict__ mv, const float* __restrict__ vv,
    float* __restrict__ q0, float* __restrict__ k0, float* __restrict__ v0)
{
  const int b = blockIdx.x / CDIM, c = blockIdx.x % CDIM;
  const int tid = threadIdx.x;
  __shared__ float xs[1024];
  for (int i = tid; i < 1024; i += 256)
    xs[i] = xr[(b * CDIM + c) * 1024 + i];
  float wq9[9], wk9[9], wv9[9];
#pragma unroll
  for (int t = 0; t < 9; ++t) {
    wq9[t] = dwq[c * 9 + t];
    wk9[t] = dwk[c * 9 + t];
    wv9[t] = dwv[c * 9 + t];
  }
  float scq = gq[c] * rsqrtf(vq[c] + 1e-5f); float shq = bq[c] - mq[c] * scq;
  float sck = gk[c] * rsqrtf(vk[c] + 1e-5f); float shk = bk[c] - mk[c] * sck;
  float scv = gv[c] * rsqrtf(vv[c] + 1e-5f); float shv = bv[c] - mv[c] * scv;
  __syncthreads();
  for (int i = tid; i < 1024; i += 256) {
    int h = i >> 5, w = i & 31;
    float aq = 0.f, ak = 0.f, av = 0.f;
#pragma unroll
    for (int dy = 0; dy < 3; ++dy) {
      int hh = h + dy - 1;
#pragma unroll
      for (int dx = 0; dx < 3; ++dx) {
        int ww = w + dx - 1;
        float xv = (hh >= 0 && hh < 32 && ww >= 0 && ww < 32) ? xs[(hh << 5) | ww] : 0.f;
        int t = dy * 3 + dx;
        aq += xv * wq9[t]; ak += xv * wk9[t]; av += xv * wv9[t];
      }
    }
    long o = (long)(b * 1024 + i) * CDIM + c;
    q0[o] = aq * scq + shq;
    k0[o] = ak * sck + shk;
    v0[o] = av * scv + shv;
  }
}

// ---------------------------------------------------------------------------
// Kernel 3/5: C[m,n] = sum_k A[m,k]*W[n,k]  (+bias[n]) (+C in-place accum)
// 64x64x16 tile, 256 threads, 4x4 microtile, float4 LDS reads.
// ---------------------------------------------------------------------------
__global__ __launch_bounds__(256) void gemm_k(
    const float* __restrict__ A, const float* __restrict__ W,
    const float* __restrict__ bias, float* __restrict__ Cd,
    int M, int K, int Nn, int flags)
{
  __shared__ float as[16][64], bs[16][64];
  const int tid = threadIdx.x;
  const int row0 = blockIdx.x * 64, col0 = blockIdx.y * 64;
  const int lm = tid >> 2, lk = (tid & 3) * 4;
  const int mt = (tid & 15) * 4, nt = (tid >> 4) * 4;
  float acc[4][4] = {};
  for (int kt = 0; kt < K; kt += 16) {
    float4 a4 = *(const float4*)&A[(long)(row0 + lm) * K + kt + lk];
    float4 b4 = *(const float4*)&W[(long)(col0 + lm) * K + kt + lk];
    as[lk + 0][lm] = a4.x; as[lk + 1][lm] = a4.y; as[lk + 2][lm] = a4.z; as[lk + 3][lm] = a4.w;
    bs[lk + 0][lm] = b4.x; bs[lk + 1][lm] = b4.y; bs[lk + 2][lm] = b4.z; bs[lk + 3][lm] = b4.w;
    __syncthreads();
#pragma unroll
    for (int k = 0; k < 16; ++k) {
      float4 av = *(const float4*)&as[k][mt];
      float4 bv = *(const float4*)&bs[k][nt];
      float am[4] = {av.x, av.y, av.z, av.w};
      float bm[4] = {bv.x, bv.y, bv.z, bv.w};
#pragma unroll
      for (int i2 = 0; i2 < 4; ++i2)
#pragma unroll
        for (int j2 = 0; j2 < 4; ++j2)
          acc[i2][j2] += am[i2] * bm[j2];
    }
    __syncthreads();
  }
#pragma unroll
  for (int i2 = 0; i2 < 4; ++i2) {
    long o = (long)(row0 + mt + i2) * Nn + col0 + nt;
    float4 r = make_float4(acc[i2][0], acc[i2][1], acc[i2][2], acc[i2][3]);
    if (flags & 1) {
      float4 bb = *(const float4*)&bias[col0 + nt];
      r.x += bb.x; r.y += bb.y; r.z += bb.z; r.w += bb.w;
    }
    if (flags & 2) {
      float4 cc = *(const float4*)&Cd[o];
      r.x += cc.x; r.y += cc.y; r.z += cc.z; r.w += cc.w;
    }
    *(float4*)&Cd[o] = r;
  }
}

// ---------------------------------------------------------------------------
// Kernel 4: flash attention.  block = (q-tile of 64 rows, b*8+h).
// 256 threads: thread (r=tid/4, sub=tid&3) owns q-row r, score cols
// sub*16..+15, and output dims sub*12..+11.  Online softmax, scale=384^-0.5.
// ---------------------------------------------------------------------------
__global__ __launch_bounds__(256) void attn_k(
    const float* __restrict__ q1, const float* __restrict__ k1,
    const float* __restrict__ v1, float* __restrict__ ao)
{
  const int qt = blockIdx.x;   // 16 q-tiles
  const int bh = blockIdx.y;   // 64
  const int b = bh >> 3, h = bh & 7;
  const int tid = threadIdx.x;
  const int r = tid >> 2, sub = tid & 3;
  const float scale = 0.051031036307982884f;  // 384^-0.5
  __shared__ float kt_s[48][68];  // [d][j], padded: 2-way max conflict
  __shared__ float vs[64][52];    // [j][d], 16B-aligned rows
  __shared__ float ps[64][65];    // probs
  float qreg[48];
  {
    const float* qp = &q1[(long)(b * 1024 + qt * 64 + r) * CDIM + h * HD];
#pragma unroll
    for (int d4 = 0; d4 < 12; ++d4) {
      float4 t = *(const float4*)&qp[d4 * 4];
      qreg[d4 * 4 + 0] = t.x; qreg[d4 * 4 + 1] = t.y;
      qreg[d4 * 4 + 2] = t.z; qreg[d4 * 4 + 3] = t.w;
    }
  }
  float m = -1e30f, l = 0.f;
  float acc[12] = {};
  const int lrow = tid >> 2;
  const int ld0 = (tid & 3) * 12;
  for (int kt2 = 0; kt2 < 16; ++kt2) {
    const float* kp = &k1[(long)(b * 1024 + kt2 * 64 + lrow) * CDIM + h * HD + ld0];
    const float* vp = &v1[(long)(b * 1024 + kt2 * 64 + lrow) * CDIM + h * HD + ld0];
#pragma unroll
    for (int t4 = 0; t4 < 3; ++t4) {
      float4 kk = *(const float4*)&kp[t4 * 4];
      kt_s[ld0 + t4 * 4 + 0][lrow] = kk.x;
      kt_s[ld0 + t4 * 4 + 1][lrow] = kk.y;
      kt_s[ld0 + t4 * 4 + 2][lrow] = kk.z;
      kt_s[ld0 + t4 * 4 + 3][lrow] = kk.w;
      float4 vv4 = *(const float4*)&vp[t4 * 4];
      *(float4*)&vs[lrow][ld0 + t4 * 4] = vv4;
    }
    __syncthreads();
    float s[16];
#pragma unroll
    for (int i2 = 0; i2 < 16; ++i2) s[i2] = 0.f;
    for (int d = 0; d < 48; ++d) {
      float qd = qreg[d];
#pragma unroll
      for (int jg = 0; jg < 4; ++jg) {
        float4 kv = *(const float4*)&kt_s[d][sub * 16 + jg * 4];
        s[jg * 4 + 0] += qd * kv.x; s[jg * 4 + 1] += qd * kv.y;
        s[jg * 4 + 2] += qd * kv.z; s[jg * 4 + 3] += qd * kv.w;
      }
    }
    float smax = -1e30f;
#pragma unroll
    for (int i2 = 0; i2 < 16; ++i2) { s[i2] *= scale; smax = fmaxf(smax, s[i2]); }
    smax = fmaxf(smax, __shfl_xor(smax, 1));
    smax = fmaxf(smax, __shfl_xor(smax, 2));
    float mnew = fmaxf(m, smax);
    float alpha = __expf(m - mnew);
    float psum = 0.f;
#pragma unroll
    for (int i2 = 0; i2 < 16; ++i2) { s[i2] = __expf(s[i2] - mnew); psum += s[i2]; }
    psum += __shfl_xor(psum, 1);
    psum += __shfl_xor(psum, 2);
    l = l * alpha + psum;
    m = mnew;
#pragma unroll
    for (int dd = 0; dd < 12; ++dd) acc[dd] *= alpha;
#pragma unroll
    for (int i2 = 0; i2 < 16; ++i2) ps[r][sub * 16 + i2] = s[i2];
    __syncthreads();
    const int d0 = sub * 12;
    for (int j = 0; j < 64; ++j) {
      float pv = ps[r][j];
      float4 v4a = *(const float4*)&vs[j][d0];
      float4 v4b = *(const float4*)&vs[j][d0 + 4];
      float4 v4c = *(const float4*)&vs[j][d0 + 8];
      acc[0] += pv * v4a.x; acc[1] += pv * v4a.y; acc[2] += pv * v4a.z; acc[3] += pv * v4a.w;
      acc[4] += pv * v4b.x; acc[5] += pv * v4b.y; acc[6] += pv * v4b.z; acc[7] += pv * v4b.w;
      acc[8] += pv * v4c.x; acc[9] += pv * v4c.y; acc[10] += pv * v4c.z; acc[11] += pv * v4c.w;
    }
    __syncthreads();
  }
  float inv = 1.f / l;
  const int d0 = sub * 12;
  float* op = &ao[(long)(b * 1024 + qt * 64 + r) * CDIM + h * HD + d0];
#pragma unroll
  for (int dd = 0; dd < 12; ++dd) op[dd] = acc[dd] * inv;
}

// ---------------------------------------------------------------------------
extern "C" void kernel_launch(void* const* d_in, const int* in_sizes, int n_in,
                              void* d_out, int out_size, void* d_ws, size_t ws_size,
                              hipStream_t stream) {
  const float* x   = (const float*)d_in[0];
  const float* cw  = (const float*)d_in[1];
  const float* dwq = (const float*)d_in[2];
  const float* dwk = (const float*)d_in[3];
  const float* dwv = (const float*)d_in[4];
  const float* gq  = (const float*)d_in[5];
  const float* bq  = (const float*)d_in[6];
  const float* mq  = (const float*)d_in[7];
  const float* vq  = (const float*)d_in[8];
  const float* gk  = (const float*)d_in[9];
  const float* bk  = (const float*)d_in[10];
  const float* mk  = (const float*)d_in[11];
  const float* vk  = (const float*)d_in[12];
  const float* gv  = (const float*)d_in[13];
  const float* bv  = (const float*)d_in[14];
  const float* mv  = (const float*)d_in[15];
  const float* vv  = (const float*)d_in[16];
  const float* wq  = (const float*)d_in[17];
  const float* wk  = (const float*)d_in[18];
  const float* wv  = (const float*)d_in[19];
  const float* wo  = (const float*)d_in[20];
  const float* bo  = (const float*)d_in[21];
  float* out = (float*)d_out;

  const size_t SLOT = (size_t)NB * NPIX * CDIM;  // 3,145,728 floats
  float* wsf   = (float*)d_ws;
  float* slotA = wsf;              // xr -> q1
  float* slotB = wsf + SLOT;       // q0 -> k1
  float* slotC = wsf + 2 * SLOT;   // k0 -> v1
  float* slotD = wsf + 3 * SLOT;   // v0 -> attn out

  fft_filter_k<<<dim3(NB * CDIM), 256, 0, stream>>>(x, cw, slotA, out);
  conv_bn_k<<<dim3(NB * CDIM), 256, 0, stream>>>(slotA, dwq, dwk, dwv,
      gq, bq, mq, vq, gk, bk, mk, vk, gv, bv, mv, vv, slotB, slotC, slotD);
  gemm_k<<<dim3(128, 6), 256, 0, stream>>>(slotB, wq, nullptr, slotA, 8192, 384, 384, 0);
  gemm_k<<<dim3(128, 6), 256, 0, stream>>>(slotC, wk, nullptr, slotB, 8192, 384, 384, 0);
  gemm_k<<<dim3(128, 6), 256, 0, stream>>>(slotD, wv, nullptr, slotC, 8192, 384, 384, 0);
  attn_k<<<dim3(16, 64), 256, 0, stream>>>(slotA, slotB, slotC, slotD);
  gemm_k<<<dim3(128, 6), 256, 0, stream>>>(slotD, wo, bo, out, 8192, 384, 384, 3);
}

// Round 2
// 319.757 us; speedup vs baseline: 2.0201x; 2.0201x over previous
//
#include <hip/hip_runtime.h>
#include <cmath>

#define CDIM 384
#define NB 8
#define NPIX 1024

typedef __attribute__((ext_vector_type(8))) short short8v;
typedef __attribute__((ext_vector_type(4))) float float4v;

__device__ __forceinline__ ushort f2bf(float f) {
  union { float f; unsigned u; } v; v.f = f;
  unsigned r = (v.u + 0x7fffu + ((v.u >> 16) & 1u)) >> 16;
  return (ushort)r;
}

// ---------------------------------------------------------------------------
// Kernel 1: spectral filter (unchanged fp32).  per (b,c) 32x32 image.
// Writes y to xr (B,C,1024) and to out (B,1024,C)  [x_fft residual base].
// ---------------------------------------------------------------------------
__global__ __launch_bounds__(256) void fft_filter_k(
    const float* __restrict__ x, const float* __restrict__ cw,
    float* __restrict__ xr, float* __restrict__ out)
{
  const int b = blockIdx.x / CDIM;
  const int c = blockIdx.x % CDIM;
  const int tid = threadIdx.x;
  __shared__ float ct[32], st[32];
  __shared__ float xs[1024];
  __shared__ float t1r[1024], t1i[1024];
  __shared__ float yr2[32][17], yi2[32][17];
  __shared__ float zr2[32][18], zi2[32][18];
  if (tid < 32) {
    float ang = (float)tid * 0.19634954084936207f;  // 2*pi/32
    ct[tid] = cosf(ang);
    st[tid] = sinf(ang);
  }
  for (int i = tid; i < 1024; i += 256)
    xs[i] = x[(b * 1024 + i) * CDIM + c];
  __syncthreads();
  for (int i = tid; i < 1024; i += 256) {
    int u = i >> 5, w = i & 31;
    float ar = 0.f, ai = 0.f;
#pragma unroll
    for (int h = 0; h < 32; ++h) {
      int idx = (u * h) & 31;
      float xv = xs[(h << 5) | w];
      ar += xv * ct[idx];
      ai -= xv * st[idx];
    }
    t1r[i] = ar; t1i[i] = ai;
  }
  __syncthreads();
  for (int i = tid; i < 544; i += 256) {
    int u = i / 17, v = i % 17;
    float fr = 0.f, fi = 0.f;
#pragma unroll
    for (int w = 0; w < 32; ++w) {
      int idx = (v * w) & 31;
      float tr = t1r[(u << 5) | w], ti = t1i[(u << 5) | w];
      fr += tr * ct[idx] + ti * st[idx];
      fi += ti * ct[idx] - tr * st[idx];
    }
    float wr = cw[((c * 32 + u) * 17 + v) * 2 + 0];
    float wi = cw[((c * 32 + u) * 17 + v) * 2 + 1];
    yr2[u][v] = fr * wr - fi * wi;
    yi2[u][v] = fr * wi + fi * wr;
  }
  __syncthreads();
  for (int i = tid; i < 544; i += 256) {
    int h = i / 17, v = i % 17;
    float zr = 0.f, zi = 0.f;
#pragma unroll
    for (int u = 0; u < 32; ++u) {
      int idx = (u * h) & 31;
      float a = yr2[u][v], bb = yi2[u][v];
      zr += a * ct[idx] - bb * st[idx];
      zi += a * st[idx] + bb * ct[idx];
    }
    zr2[h][v] = zr; zi2[h][v] = zi;
  }
  __syncthreads();
  for (int i = tid; i < 1024; i += 256) {
    int h = i >> 5, w = i & 31;
    float acc = zr2[h][0] + ((w & 1) ? -zr2[h][16] : zr2[h][16]);
#pragma unroll
    for (int v = 1; v < 16; ++v) {
      int idx = (v * w) & 31;
      acc += 2.f * (zr2[h][v] * ct[idx] - zi2[h][v] * st[idx]);
    }
    float y = acc * (1.0f / 1024.0f);
    xr[(b * CDIM + c) * 1024 + i] = y;
    out[(b * 1024 + i) * CDIM + c] = y;
  }
}

// ---------------------------------------------------------------------------
// Kernel 2: depthwise 3x3 conv + BN -> bf16 outputs (B,N,C)
// ---------------------------------------------------------------------------
__global__ __launch_bounds__(256) void conv_bn_k(
    const float* __restrict__ xr,
    const float* __restrict__ dwq, const float* __restrict__ dwk, const float* __restrict__ dwv,
    const float* __restrict__ gq, const float* __restrict__ bq, const float* __restrict__ mq, const float* __restrict__ vq,
    const float* __restrict__ gk, const float* __restrict__ bk, const float* __restrict__ mk, const float* __restrict__ vk,
    const float* __restrict__ gv, const float* __restrict__ bv, const float* __restrict__ mv, const float* __restrict__ vv,
    ushort* __restrict__ q0, ushort* __restrict__ k0, ushort* __restrict__ v0)
{
  const int b = blockIdx.x / CDIM, c = blockIdx.x % CDIM;
  const int tid = threadIdx.x;
  __shared__ float xs[1024];
  for (int i = tid; i < 1024; i += 256)
    xs[i] = xr[(b * CDIM + c) * 1024 + i];
  float wq9[9], wk9[9], wv9[9];
#pragma unroll
  for (int t = 0; t < 9; ++t) {
    wq9[t] = dwq[c * 9 + t];
    wk9[t] = dwk[c * 9 + t];
    wv9[t] = dwv[c * 9 + t];
  }
  float scq = gq[c] * rsqrtf(vq[c] + 1e-5f); float shq = bq[c] - mq[c] * scq;
  float sck = gk[c] * rsqrtf(vk[c] + 1e-5f); float shk = bk[c] - mk[c] * sck;
  float scv = gv[c] * rsqrtf(vv[c] + 1e-5f); float shv = bv[c] - mv[c] * scv;
  __syncthreads();
  for (int i = tid; i < 1024; i += 256) {
    int h = i >> 5, w = i & 31;
    float aq = 0.f, ak = 0.f, av = 0.f;
#pragma unroll
    for (int dy = 0; dy < 3; ++dy) {
      int hh = h + dy - 1;
#pragma unroll
      for (int dx = 0; dx < 3; ++dx) {
        int ww = w + dx - 1;
        float xv = (hh >= 0 && hh < 32 && ww >= 0 && ww < 32) ? xs[(hh << 5) | ww] : 0.f;
        int t = dy * 3 + dx;
        aq += xv * wq9[t]; ak += xv * wk9[t]; av += xv * wv9[t];
      }
    }
    long o = (long)(b * 1024 + i) * CDIM + c;
    q0[o] = f2bf(aq * scq + shq);
    k0[o] = f2bf(ak * sck + shk);
    v0[o] = f2bf(av * scv + shv);
  }
}

// ---------------------------------------------------------------------------
// Kernel 2b: convert the 4 projection weights to bf16
// ---------------------------------------------------------------------------
__global__ __launch_bounds__(256) void wconv_k(
    const float* __restrict__ a, const float* __restrict__ b,
    const float* __restrict__ c, const float* __restrict__ d,
    ushort* __restrict__ oa, ushort* __restrict__ ob,
    ushort* __restrict__ oc, ushort* __restrict__ od)
{
  int i = blockIdx.x * 256 + threadIdx.x;
  if (i * 4 >= CDIM * CDIM) return;
  float4 va = *(const float4*)&a[i * 4];
  float4 vb = *(const float4*)&b[i * 4];
  float4 vc = *(const float4*)&c[i * 4];
  float4 vd = *(const float4*)&d[i * 4];
  ushort4 ra = { f2bf(va.x), f2bf(va.y), f2bf(va.z), f2bf(va.w) };
  ushort4 rb = { f2bf(vb.x), f2bf(vb.y), f2bf(vb.z), f2bf(vb.w) };
  ushort4 rc = { f2bf(vc.x), f2bf(vc.y), f2bf(vc.z), f2bf(vc.w) };
  ushort4 rd = { f2bf(vd.x), f2bf(vd.y), f2bf(vd.z), f2bf(vd.w) };
  *(ushort4*)&oa[i * 4] = ra;
  *(ushort4*)&ob[i * 4] = rb;
  *(ushort4*)&oc[i * 4] = rc;
  *(ushort4*)&od[i * 4] = rd;
}

// ---------------------------------------------------------------------------
// Kernel 3/5: MFMA GEMM  C[m,n'] = sum_k A[m,k] W[n',k]
// tile 128x64, BK=64, 4 waves (2x2), padded LDS (stride 72 bf16 = 144B).
// flags==0: bf16 store.  flags==1: fp32 RMW  out += acc + bias.
// ---------------------------------------------------------------------------
__global__ __launch_bounds__(256) void gemm_bf16_k(
    const ushort* __restrict__ A, const ushort* __restrict__ Wb,
    const float* __restrict__ bias, void* __restrict__ Cd, int flags)
{
  __shared__ ushort As[128][72];
  __shared__ ushort Ws[64][72];
  const int tid = threadIdx.x;
  const int w = tid >> 6, lane = tid & 63;
  const int l15 = lane & 15, l16 = lane >> 4;
  const int wm = w >> 1, wn = w & 1;
  const int row0 = blockIdx.x * 128, col0 = blockIdx.y * 64;
  float4v acc[4][2];
#pragma unroll
  for (int i = 0; i < 4; ++i)
#pragma unroll
    for (int j = 0; j < 2; ++j) acc[i][j] = (float4v){0.f, 0.f, 0.f, 0.f};
  for (int kt = 0; kt < CDIM; kt += 64) {
    if (kt) __syncthreads();
    for (int c = tid; c < 1024; c += 256) {
      int r = c >> 3, s = c & 7;
      *(uint4*)&As[r][s * 8] = *(const uint4*)&A[(long)(row0 + r) * CDIM + kt + s * 8];
    }
    for (int c = tid; c < 512; c += 256) {
      int r = c >> 3, s = c & 7;
      *(uint4*)&Ws[r][s * 8] = *(const uint4*)&Wb[(long)(col0 + r) * CDIM + kt + s * 8];
    }
    __syncthreads();
#pragma unroll
    for (int s = 0; s < 2; ++s) {
      short8v a[4], bfr[2];
#pragma unroll
      for (int i = 0; i < 4; ++i)
        a[i] = *(const short8v*)&As[wm * 64 + i * 16 + l15][s * 32 + l16 * 8];
#pragma unroll
      for (int j = 0; j < 2; ++j)
        bfr[j] = *(const short8v*)&Ws[wn * 32 + j * 16 + l15][s * 32 + l16 * 8];
#pragma unroll
      for (int i = 0; i < 4; ++i)
#pragma unroll
        for (int j = 0; j < 2; ++j)
          acc[i][j] = __builtin_amdgcn_mfma_f32_16x16x32_bf16(a[i], bfr[j], acc[i][j], 0, 0, 0);
    }
  }
#pragma unroll
  for (int i = 0; i < 4; ++i)
#pragma unroll
    for (int j = 0; j < 2; ++j) {
      int col = col0 + wn * 32 + j * 16 + l15;
      int rbase = row0 + wm * 64 + i * 16 + l16 * 4;
#pragma unroll
      for (int r = 0; r < 4; ++r) {
        long o = (long)(rbase + r) * CDIM + col;
        if (flags == 0) ((ushort*)Cd)[o] = f2bf(acc[i][j][r]);
        else            ((float*)Cd)[o] += acc[i][j][r] + bias[col];
      }
    }
}

// ---------------------------------------------------------------------------
// Kernel 4: MFMA flash attention.  block = (64-row Q tile, b*8+h), 4 waves.
// d=48 zero-padded to 64 for QK^T; V stored d-major for PV B-operand.
// ---------------------------------------------------------------------------
__global__ __launch_bounds__(256) void attn_mfma_k(
    const ushort* __restrict__ q1, const ushort* __restrict__ k1,
    const ushort* __restrict__ v1, ushort* __restrict__ ao)
{
  const int qt = blockIdx.x, bh = blockIdx.y;
  const int b = bh >> 3, h = bh & 7;
  const int tid = threadIdx.x;
  const int w = tid >> 6, lane = tid & 63;
  const int l15 = lane & 15, l16 = lane >> 4;
  __shared__ ushort Qs[64][72], Ks[64][72], Ps[64][72];
  __shared__ ushort Vt[48][72];
  const float scale = 0.051031036307982884f;  // 384^-0.5
  const long base = (long)b * NPIX * CDIM + h * 48;
  uint4 z4 = {0u, 0u, 0u, 0u};
  for (int i = tid; i < 128; i += 256) {       // zero-pad d=48..63
    int r = i >> 1, s = i & 1;
    *(uint4*)&Qs[r][48 + s * 8] = z4;
    *(uint4*)&Ks[r][48 + s * 8] = z4;
  }
  for (int i = tid; i < 384; i += 256) {       // stage Q once
    int r = i / 6, s = i - r * 6;
    *(uint4*)&Qs[r][s * 8] = *(const uint4*)&q1[base + (long)(qt * 64 + r) * CDIM + s * 8];
  }
  float mrun[4], lrun[4];
  float4v accO[3];
#pragma unroll
  for (int r = 0; r < 4; ++r) { mrun[r] = -1e30f; lrun[r] = 0.f; }
#pragma unroll
  for (int fd = 0; fd < 3; ++fd) accO[fd] = (float4v){0.f, 0.f, 0.f, 0.f};

  for (int kt = 0; kt < 16; ++kt) {
    if (kt) __syncthreads();                   // prev PV done with Ks/Vt
    for (int i = tid; i < 384; i += 256) {
      int r = i / 6, s = i - r * 6;
      *(uint4*)&Ks[r][s * 8] = *(const uint4*)&k1[base + (long)(kt * 64 + r) * CDIM + s * 8];
    }
    for (int i = tid; i < 3072; i += 256) {    // V transpose -> Vt[d][n]
      int n = i / 48, d = i - n * 48;
      Vt[d][n] = v1[base + (long)(kt * 64 + n) * CDIM + d];
    }
    __syncthreads();
    // QK^T: wave w -> S rows w*16..w*16+15, all 64 cols
    short8v qa0 = *(const short8v*)&Qs[w * 16 + l15][l16 * 8];
    short8v qa1 = *(const short8v*)&Qs[w * 16 + l15][32 + l16 * 8];
    float4v sacc[4];
#pragma unroll
    for (int fc = 0; fc < 4; ++fc) {
      sacc[fc] = (float4v){0.f, 0.f, 0.f, 0.f};
      short8v kb0 = *(const short8v*)&Ks[fc * 16 + l15][l16 * 8];
      short8v kb1 = *(const short8v*)&Ks[fc * 16 + l15][32 + l16 * 8];
      sacc[fc] = __builtin_amdgcn_mfma_f32_16x16x32_bf16(qa0, kb0, sacc[fc], 0, 0, 0);
      sacc[fc] = __builtin_amdgcn_mfma_f32_16x16x32_bf16(qa1, kb1, sacc[fc], 0, 0, 0);
    }
    // online softmax; lane holds rows l16*4+r, cols fc*16+l15
    float pmax[4] = {-1e30f, -1e30f, -1e30f, -1e30f};
#pragma unroll
    for (int fc = 0; fc < 4; ++fc)
#pragma unroll
      for (int r = 0; r < 4; ++r)
        pmax[r] = fmaxf(pmax[r], sacc[fc][r] * scale);
#pragma unroll
    for (int r = 0; r < 4; ++r) {
      pmax[r] = fmaxf(pmax[r], __shfl_xor(pmax[r], 1));
      pmax[r] = fmaxf(pmax[r], __shfl_xor(pmax[r], 2));
      pmax[r] = fmaxf(pmax[r], __shfl_xor(pmax[r], 4));
      pmax[r] = fmaxf(pmax[r], __shfl_xor(pmax[r], 8));
    }
    float alpha[4], psum[4];
#pragma unroll
    for (int r = 0; r < 4; ++r) {
      float mnew = fmaxf(mrun[r], pmax[r]);
      alpha[r] = __expf(mrun[r] - mnew);
      mrun[r] = mnew;
      psum[r] = 0.f;
    }
#pragma unroll
    for (int fc = 0; fc < 4; ++fc)
#pragma unroll
      for (int r = 0; r < 4; ++r) {
        float p = __expf(sacc[fc][r] * scale - mrun[r]);
        psum[r] += p;
        Ps[w * 16 + l16 * 4 + r][fc * 16 + l15] = f2bf(p);
      }
#pragma unroll
    for (int r = 0; r < 4; ++r) {
      psum[r] += __shfl_xor(psum[r], 1);
      psum[r] += __shfl_xor(psum[r], 2);
      psum[r] += __shfl_xor(psum[r], 4);
      psum[r] += __shfl_xor(psum[r], 8);
      lrun[r] = lrun[r] * alpha[r] + psum[r];
    }
#pragma unroll
    for (int fd = 0; fd < 3; ++fd)
#pragma unroll
      for (int r = 0; r < 4; ++r) accO[fd][r] *= alpha[r];
    __syncthreads();                           // order Ps writes vs vector reads
    // PV: O(16x48) += P(16x64) . V(64x48)
    short8v pa0 = *(const short8v*)&Ps[w * 16 + l15][l16 * 8];
    short8v pa1 = *(const short8v*)&Ps[w * 16 + l15][32 + l16 * 8];
#pragma unroll
    for (int fd = 0; fd < 3; ++fd) {
      short8v vb0 = *(const short8v*)&Vt[fd * 16 + l15][l16 * 8];
      short8v vb1 = *(const short8v*)&Vt[fd * 16 + l15][32 + l16 * 8];
      accO[fd] = __builtin_amdgcn_mfma_f32_16x16x32_bf16(pa0, vb0, accO[fd], 0, 0, 0);
      accO[fd] = __builtin_amdgcn_mfma_f32_16x16x32_bf16(pa1, vb1, accO[fd], 0, 0, 0);
    }
  }
#pragma unroll
  for (int fd = 0; fd < 3; ++fd)
#pragma unroll
    for (int r = 0; r < 4; ++r) {
      int qrow = qt * 64 + w * 16 + l16 * 4 + r;
      ao[base + (long)qrow * CDIM + fd * 16 + l15] = f2bf(accO[fd][r] / lrun[r]);
    }
}

// ---------------------------------------------------------------------------
extern "C" void kernel_launch(void* const* d_in, const int* in_sizes, int n_in,
                              void* d_out, int out_size, void* d_ws, size_t ws_size,
                              hipStream_t stream) {
  const float* x   = (const float*)d_in[0];
  const float* cw  = (const float*)d_in[1];
  const float* dwq = (const float*)d_in[2];
  const float* dwk = (const float*)d_in[3];
  const float* dwv = (const float*)d_in[4];
  const float* gq  = (const float*)d_in[5];
  const float* bq  = (const float*)d_in[6];
  const float* mq  = (const float*)d_in[7];
  const float* vq  = (const float*)d_in[8];
  const float* gk  = (const float*)d_in[9];
  const float* bk  = (const float*)d_in[10];
  const float* mk  = (const float*)d_in[11];
  const float* vk  = (const float*)d_in[12];
  const float* gv  = (const float*)d_in[13];
  const float* bv  = (const float*)d_in[14];
  const float* mv  = (const float*)d_in[15];
  const float* vv  = (const float*)d_in[16];
  const float* wq  = (const float*)d_in[17];
  const float* wk  = (const float*)d_in[18];
  const float* wv  = (const float*)d_in[19];
  const float* wo  = (const float*)d_in[20];
  const float* bo  = (const float*)d_in[21];
  float* out = (float*)d_out;

  char* wsb = (char*)d_ws;
  const size_t SLOTB = (size_t)NB * NPIX * CDIM * 4;   // 12,582,912 B
  float*  xr  = (float*)(wsb);
  ushort* q1  = (ushort*)(wsb);
  ushort* k1  = (ushort*)(wsb + SLOTB / 2);
  ushort* q0  = (ushort*)(wsb + SLOTB);
  ushort* k0  = (ushort*)(wsb + SLOTB + SLOTB / 2);
  ushort* v0  = (ushort*)(wsb + 2 * SLOTB);
  ushort* v1  = (ushort*)(wsb + 2 * SLOTB + SLOTB / 2);
  ushort* ao  = (ushort*)(wsb + 3 * SLOTB);
  ushort* wqb = (ushort*)(wsb + 3 * SLOTB + SLOTB / 2);
  ushort* wkb = wqb + CDIM * CDIM;
  ushort* wvb = wkb + CDIM * CDIM;
  ushort* wob = wvb + CDIM * CDIM;

  wconv_k<<<dim3(144), 256, 0, stream>>>(wq, wk, wv, wo, wqb, wkb, wvb, wob);
  fft_filter_k<<<dim3(NB * CDIM), 256, 0, stream>>>(x, cw, xr, out);
  conv_bn_k<<<dim3(NB * CDIM), 256, 0, stream>>>(xr, dwq, dwk, dwv,
      gq, bq, mq, vq, gk, bk, mk, vk, gv, bv, mv, vv, q0, k0, v0);
  gemm_bf16_k<<<dim3(64, 6), 256, 0, stream>>>(q0, wqb, nullptr, q1, 0);
  gemm_bf16_k<<<dim3(64, 6), 256, 0, stream>>>(k0, wkb, nullptr, k1, 0);
  gemm_bf16_k<<<dim3(64, 6), 256, 0, stream>>>(v0, wvb, nullptr, v1, 0);
  attn_mfma_k<<<dim3(16, 64), 256, 0, stream>>>(q1, k1, v1, ao);
  gemm_bf16_k<<<dim3(64, 6), 256, 0, stream>>>(ao, wob, bo, out, 1);
}

// Round 3
// 259.876 us; speedup vs baseline: 2.4856x; 1.2304x over previous
//
#include <hip/hip_runtime.h>
#include <cmath>

#define CDIM 384
#define NB 8
#define NPIX 1024

typedef __attribute__((ext_vector_type(8))) short short8v;
typedef __attribute__((ext_vector_type(4))) float float4v;

__device__ __forceinline__ ushort f2bf(float f) {
  union { float f; unsigned u; } v; v.f = f;
  unsigned r = (v.u + 0x7fffu + ((v.u >> 16) & 1u)) >> 16;
  return (ushort)r;
}

// ---------------------------------------------------------------------------
// Kernel 1: spectral filter (fp32).  per (b,c) 32x32 image.
// Writes y to xr (B,C,1024) and to out (B,1024,C)  [x_fft residual base].
// ---------------------------------------------------------------------------
__global__ __launch_bounds__(256) void fft_filter_k(
    const float* __restrict__ x, const float* __restrict__ cw,
    float* __restrict__ xr, float* __restrict__ out)
{
  const int b = blockIdx.x / CDIM;
  const int c = blockIdx.x % CDIM;
  const int tid = threadIdx.x;
  __shared__ float ct[32], st[32];
  __shared__ float xs[1024];
  __shared__ float t1r[1024], t1i[1024];
  __shared__ float yr2[32][17], yi2[32][17];
  __shared__ float zr2[32][18], zi2[32][18];
  if (tid < 32) {
    float ang = (float)tid * 0.19634954084936207f;  // 2*pi/32
    ct[tid] = cosf(ang);
    st[tid] = sinf(ang);
  }
  for (int i = tid; i < 1024; i += 256)
    xs[i] = x[(b * 1024 + i) * CDIM + c];
  __syncthreads();
  for (int i = tid; i < 1024; i += 256) {
    int u = i >> 5, w = i & 31;
    float ar = 0.f, ai = 0.f;
#pragma unroll
    for (int h = 0; h < 32; ++h) {
      int idx = (u * h) & 31;
      float xv = xs[(h << 5) | w];
      ar += xv * ct[idx];
      ai -= xv * st[idx];
    }
    t1r[i] = ar; t1i[i] = ai;
  }
  __syncthreads();
  for (int i = tid; i < 544; i += 256) {
    int u = i / 17, v = i % 17;
    float fr = 0.f, fi = 0.f;
#pragma unroll
    for (int w = 0; w < 32; ++w) {
      int idx = (v * w) & 31;
      float tr = t1r[(u << 5) | w], ti = t1i[(u << 5) | w];
      fr += tr * ct[idx] + ti * st[idx];
      fi += ti * ct[idx] - tr * st[idx];
    }
    float wr = cw[((c * 32 + u) * 17 + v) * 2 + 0];
    float wi = cw[((c * 32 + u) * 17 + v) * 2 + 1];
    yr2[u][v] = fr * wr - fi * wi;
    yi2[u][v] = fr * wi + fi * wr;
  }
  __syncthreads();
  for (int i = tid; i < 544; i += 256) {
    int h = i / 17, v = i % 17;
    float zr = 0.f, zi = 0.f;
#pragma unroll
    for (int u = 0; u < 32; ++u) {
      int idx = (u * h) & 31;
      float a = yr2[u][v], bb = yi2[u][v];
      zr += a * ct[idx] - bb * st[idx];
      zi += a * st[idx] + bb * ct[idx];
    }
    zr2[h][v] = zr; zi2[h][v] = zi;
  }
  __syncthreads();
  for (int i = tid; i < 1024; i += 256) {
    int h = i >> 5, w = i & 31;
    float acc = zr2[h][0] + ((w & 1) ? -zr2[h][16] : zr2[h][16]);
#pragma unroll
    for (int v = 1; v < 16; ++v) {
      int idx = (v * w) & 31;
      acc += 2.f * (zr2[h][v] * ct[idx] - zi2[h][v] * st[idx]);
    }
    float y = acc * (1.0f / 1024.0f);
    xr[(b * CDIM + c) * 1024 + i] = y;
    out[(b * 1024 + i) * CDIM + c] = y;
  }
}

// ---------------------------------------------------------------------------
// Kernel 2: depthwise 3x3 conv + BN -> bf16 outputs (B,N,C)
// ---------------------------------------------------------------------------
__global__ __launch_bounds__(256) void conv_bn_k(
    const float* __restrict__ xr,
    const float* __restrict__ dwq, const float* __restrict__ dwk, const float* __restrict__ dwv,
    const float* __restrict__ gq, const float* __restrict__ bq, const float* __restrict__ mq, const float* __restrict__ vq,
    const float* __restrict__ gk, const float* __restrict__ bk, const float* __restrict__ mk, const float* __restrict__ vk,
    const float* __restrict__ gv, const float* __restrict__ bv, const float* __restrict__ mv, const float* __restrict__ vv,
    ushort* __restrict__ q0, ushort* __restrict__ k0, ushort* __restrict__ v0)
{
  const int b = blockIdx.x / CDIM, c = blockIdx.x % CDIM;
  const int tid = threadIdx.x;
  __shared__ float xs[1024];
  for (int i = tid; i < 1024; i += 256)
    xs[i] = xr[(b * CDIM + c) * 1024 + i];
  float wq9[9], wk9[9], wv9[9];
#pragma unroll
  for (int t = 0; t < 9; ++t) {
    wq9[t] = dwq[c * 9 + t];
    wk9[t] = dwk[c * 9 + t];
    wv9[t] = dwv[c * 9 + t];
  }
  float scq = gq[c] * rsqrtf(vq[c] + 1e-5f); float shq = bq[c] - mq[c] * scq;
  float sck = gk[c] * rsqrtf(vk[c] + 1e-5f); float shk = bk[c] - mk[c] * sck;
  float scv = gv[c] * rsqrtf(vv[c] + 1e-5f); float shv = bv[c] - mv[c] * scv;
  __syncthreads();
  for (int i = tid; i < 1024; i += 256) {
    int h = i >> 5, w = i & 31;
    float aq = 0.f, ak = 0.f, av = 0.f;
#pragma unroll
    for (int dy = 0; dy < 3; ++dy) {
      int hh = h + dy - 1;
#pragma unroll
      for (int dx = 0; dx < 3; ++dx) {
        int ww = w + dx - 1;
        float xv = (hh >= 0 && hh < 32 && ww >= 0 && ww < 32) ? xs[(hh << 5) | ww] : 0.f;
        int t = dy * 3 + dx;
        aq += xv * wq9[t]; ak += xv * wk9[t]; av += xv * wv9[t];
      }
    }
    long o = (long)(b * 1024 + i) * CDIM + c;
    q0[o] = f2bf(aq * scq + shq);
    k0[o] = f2bf(ak * sck + shk);
    v0[o] = f2bf(av * scv + shv);
  }
}

// ---------------------------------------------------------------------------
// Kernel 2b: convert the 4 projection weights to bf16
// ---------------------------------------------------------------------------
__global__ __launch_bounds__(256) void wconv_k(
    const float* __restrict__ a, const float* __restrict__ b,
    const float* __restrict__ c, const float* __restrict__ d,
    ushort* __restrict__ oa, ushort* __restrict__ ob,
    ushort* __restrict__ oc, ushort* __restrict__ od)
{
  int i = blockIdx.x * 256 + threadIdx.x;
  if (i * 4 >= CDIM * CDIM) return;
  float4 va = *(const float4*)&a[i * 4];
  float4 vb = *(const float4*)&b[i * 4];
  float4 vc = *(const float4*)&c[i * 4];
  float4 vd = *(const float4*)&d[i * 4];
  ushort4 ra = { f2bf(va.x), f2bf(va.y), f2bf(va.z), f2bf(va.w) };
  ushort4 rb = { f2bf(vb.x), f2bf(vb.y), f2bf(vb.z), f2bf(vb.w) };
  ushort4 rc = { f2bf(vc.x), f2bf(vc.y), f2bf(vc.z), f2bf(vc.w) };
  ushort4 rd = { f2bf(vd.x), f2bf(vd.y), f2bf(vd.z), f2bf(vd.w) };
  *(ushort4*)&oa[i * 4] = ra;
  *(ushort4*)&ob[i * 4] = rb;
  *(ushort4*)&oc[i * 4] = rc;
  *(ushort4*)&od[i * 4] = rd;
}

// ---------------------------------------------------------------------------
// MFMA GEMM body  C[m,n'] = sum_k A[m,k] W[n',k]
// tile 128x64, BK=64, 4 waves (2x2), padded LDS (stride 72 bf16 = 144B).
// flags==0: bf16 store.  flags==1: fp32 RMW  out += acc + bias.
// ---------------------------------------------------------------------------
__device__ __forceinline__ void gemm_body(
    const ushort* __restrict__ A, const ushort* __restrict__ Wb,
    const float* __restrict__ bias, void* __restrict__ Cd, int flags,
    int bx, int by)
{
  __shared__ ushort As[128][72];
  __shared__ ushort Ws[64][72];
  const int tid = threadIdx.x;
  const int w = tid >> 6, lane = tid & 63;
  const int l15 = lane & 15, l16 = lane >> 4;
  const int wm = w >> 1, wn = w & 1;
  const int row0 = bx * 128, col0 = by * 64;
  float4v acc[4][2];
#pragma unroll
  for (int i = 0; i < 4; ++i)
#pragma unroll
    for (int j = 0; j < 2; ++j) acc[i][j] = (float4v){0.f, 0.f, 0.f, 0.f};
  for (int kt = 0; kt < CDIM; kt += 64) {
    if (kt) __syncthreads();
    for (int c = tid; c < 1024; c += 256) {
      int r = c >> 3, s = c & 7;
      *(uint4*)&As[r][s * 8] = *(const uint4*)&A[(long)(row0 + r) * CDIM + kt + s * 8];
    }
    for (int c = tid; c < 512; c += 256) {
      int r = c >> 3, s = c & 7;
      *(uint4*)&Ws[r][s * 8] = *(const uint4*)&Wb[(long)(col0 + r) * CDIM + kt + s * 8];
    }
    __syncthreads();
#pragma unroll
    for (int s = 0; s < 2; ++s) {
      short8v a[4], bfr[2];
#pragma unroll
      for (int i = 0; i < 4; ++i)
        a[i] = *(const short8v*)&As[wm * 64 + i * 16 + l15][s * 32 + l16 * 8];
#pragma unroll
      for (int j = 0; j < 2; ++j)
        bfr[j] = *(const short8v*)&Ws[wn * 32 + j * 16 + l15][s * 32 + l16 * 8];
#pragma unroll
      for (int i = 0; i < 4; ++i)
#pragma unroll
        for (int j = 0; j < 2; ++j)
          acc[i][j] = __builtin_amdgcn_mfma_f32_16x16x32_bf16(a[i], bfr[j], acc[i][j], 0, 0, 0);
    }
  }
#pragma unroll
  for (int i = 0; i < 4; ++i)
#pragma unroll
    for (int j = 0; j < 2; ++j) {
      int col = col0 + wn * 32 + j * 16 + l15;
      int rbase = row0 + wm * 64 + i * 16 + l16 * 4;
#pragma unroll
      for (int r = 0; r < 4; ++r) {
        long o = (long)(rbase + r) * CDIM + col;
        if (flags == 0) ((ushort*)Cd)[o] = f2bf(acc[i][j][r]);
        else            ((float*)Cd)[o] += acc[i][j][r] + bias[col];
      }
    }
}

// fused q/k/v projection GEMMs (blockIdx.z selects)
__global__ __launch_bounds__(256) void gemm_qkv_k(
    const ushort* __restrict__ q0, const ushort* __restrict__ k0, const ushort* __restrict__ v0,
    const ushort* __restrict__ wqb, const ushort* __restrict__ wkb, const ushort* __restrict__ wvb,
    ushort* __restrict__ q1, ushort* __restrict__ k1, ushort* __restrict__ v1)
{
  const int z = blockIdx.z;
  const ushort* A  = z == 0 ? q0  : z == 1 ? k0  : v0;
  const ushort* Wb = z == 0 ? wqb : z == 1 ? wkb : wvb;
  ushort*       C  = z == 0 ? q1  : z == 1 ? k1  : v1;
  gemm_body(A, Wb, nullptr, C, 0, blockIdx.x, blockIdx.y);
}

// final projection: out += A@wo^T + bo
__global__ __launch_bounds__(256) void gemm_out_k(
    const ushort* __restrict__ A, const ushort* __restrict__ Wb,
    const float* __restrict__ bias, float* __restrict__ Cd)
{
  gemm_body(A, Wb, bias, Cd, 1, blockIdx.x, blockIdx.y);
}

// ---------------------------------------------------------------------------
// Kernel 3b: V transpose  v1 (b,n,h*48+d) -> vt ((b*8+h)*48+d, n)
// block = (bh, ntile of 64).  uint-typed padded LDS, all accesses <=2-way.
// ---------------------------------------------------------------------------
__global__ __launch_bounds__(256) void vtrans_k(
    const ushort* __restrict__ v1, ushort* __restrict__ vt)
{
  const int bh = blockIdx.x, b = bh >> 3, h = bh & 7;
  const int n0 = blockIdx.y * 64;
  const int tid = threadIdx.x;
  __shared__ unsigned Lu[64][49];
  for (int i = tid; i < 384; i += 256) {
    int r = i / 6, s = i - r * 6;
    uint4 p = *(const uint4*)&v1[(long)(b * 1024 + n0 + r) * CDIM + h * 48 + s * 8];
    unsigned d0 = s * 8;
    Lu[r][d0 + 0] = p.x & 0xffffu;        Lu[r][d0 + 1] = p.x >> 16;
    Lu[r][d0 + 2] = p.y & 0xffffu;        Lu[r][d0 + 3] = p.y >> 16;
    Lu[r][d0 + 4] = p.z & 0xffffu;        Lu[r][d0 + 5] = p.z >> 16;
    Lu[r][d0 + 6] = p.w & 0xffffu;        Lu[r][d0 + 7] = p.w >> 16;
  }
  __syncthreads();
  for (int i = tid; i < 384; i += 256) {
    int d = i >> 3, s = i & 7;
    uint4 o;
    o.x = Lu[s * 8 + 0][d] | (Lu[s * 8 + 1][d] << 16);
    o.y = Lu[s * 8 + 2][d] | (Lu[s * 8 + 3][d] << 16);
    o.z = Lu[s * 8 + 4][d] | (Lu[s * 8 + 5][d] << 16);
    o.w = Lu[s * 8 + 6][d] | (Lu[s * 8 + 7][d] << 16);
    *(uint4*)&vt[((long)bh * 48 + d) * NPIX + n0 + s * 8] = o;
  }
}

// ---------------------------------------------------------------------------
// Kernel 4: MFMA flash attention.  block = (b*8+h, 64-row Q tile), 4 waves.
// grid.x = bh so all q-tiles of one (b,h) share an XCD (stride 64 % 8 == 0).
// V comes pre-transposed from vt.
// ---------------------------------------------------------------------------
__global__ __launch_bounds__(256) void attn_mfma_k(
    const ushort* __restrict__ q1, const ushort* __restrict__ k1,
    const ushort* __restrict__ vt, ushort* __restrict__ ao)
{
  const int bh = blockIdx.x, qt = blockIdx.y;
  const int b = bh >> 3, h = bh & 7;
  const int tid = threadIdx.x;
  const int w = tid >> 6, lane = tid & 63;
  const int l15 = lane & 15, l16 = lane >> 4;
  __shared__ ushort Qs[64][72], Ks[64][72], Ps[64][72];
  __shared__ ushort Vs[48][72];
  const float scale = 0.051031036307982884f;  // 384^-0.5
  const long base = (long)b * NPIX * CDIM + h * 48;
  const long vbase = (long)bh * 48 * NPIX;
  uint4 z4 = {0u, 0u, 0u, 0u};
  for (int i = tid; i < 128; i += 256) {       // zero-pad d=48..63
    int r = i >> 1, s = i & 1;
    *(uint4*)&Qs[r][48 + s * 8] = z4;
    *(uint4*)&Ks[r][48 + s * 8] = z4;
  }
  for (int i = tid; i < 384; i += 256) {       // stage Q once
    int r = i / 6, s = i - r * 6;
    *(uint4*)&Qs[r][s * 8] = *(const uint4*)&q1[base + (long)(qt * 64 + r) * CDIM + s * 8];
  }
  float mrun[4], lrun[4];
  float4v accO[3];
#pragma unroll
  for (int r = 0; r < 4; ++r) { mrun[r] = -1e30f; lrun[r] = 0.f; }
#pragma unroll
  for (int fd = 0; fd < 3; ++fd) accO[fd] = (float4v){0.f, 0.f, 0.f, 0.f};

  for (int kt = 0; kt < 16; ++kt) {
    if (kt) __syncthreads();                   // prev iter done with Ks/Vs
    for (int i = tid; i < 768; i += 256) {
      if (i < 384) {
        int r = i / 6, s = i - r * 6;
        *(uint4*)&Ks[r][s * 8] = *(const uint4*)&k1[base + (long)(kt * 64 + r) * CDIM + s * 8];
      } else {
        int j = i - 384, d = j >> 3, s = j & 7;
        *(uint4*)&Vs[d][s * 8] = *(const uint4*)&vt[vbase + (long)d * NPIX + kt * 64 + s * 8];
      }
    }
    __syncthreads();
    // QK^T: wave w -> S rows w*16..w*16+15, all 64 cols
    short8v qa0 = *(const short8v*)&Qs[w * 16 + l15][l16 * 8];
    short8v qa1 = *(const short8v*)&Qs[w * 16 + l15][32 + l16 * 8];
    float4v sacc[4];
#pragma unroll
    for (int fc = 0; fc < 4; ++fc) {
      sacc[fc] = (float4v){0.f, 0.f, 0.f, 0.f};
      short8v kb0 = *(const short8v*)&Ks[fc * 16 + l15][l16 * 8];
      short8v kb1 = *(const short8v*)&Ks[fc * 16 + l15][32 + l16 * 8];
      sacc[fc] = __builtin_amdgcn_mfma_f32_16x16x32_bf16(qa0, kb0, sacc[fc], 0, 0, 0);
      sacc[fc] = __builtin_amdgcn_mfma_f32_16x16x32_bf16(qa1, kb1, sacc[fc], 0, 0, 0);
    }
    // online softmax; lane holds rows l16*4+r, cols fc*16+l15
    float pmax[4] = {-1e30f, -1e30f, -1e30f, -1e30f};
#pragma unroll
    for (int fc = 0; fc < 4; ++fc)
#pragma unroll
      for (int r = 0; r < 4; ++r)
        pmax[r] = fmaxf(pmax[r], sacc[fc][r] * scale);
#pragma unroll
    for (int r = 0; r < 4; ++r) {
      pmax[r] = fmaxf(pmax[r], __shfl_xor(pmax[r], 1));
      pmax[r] = fmaxf(pmax[r], __shfl_xor(pmax[r], 2));
      pmax[r] = fmaxf(pmax[r], __shfl_xor(pmax[r], 4));
      pmax[r] = fmaxf(pmax[r], __shfl_xor(pmax[r], 8));
    }
    float alpha[4], psum[4];
#pragma unroll
    for (int r = 0; r < 4; ++r) {
      float mnew = fmaxf(mrun[r], pmax[r]);
      alpha[r] = __expf(mrun[r] - mnew);
      mrun[r] = mnew;
      psum[r] = 0.f;
    }
#pragma unroll
    for (int fc = 0; fc < 4; ++fc)
#pragma unroll
      for (int r = 0; r < 4; ++r) {
        float p = __expf(sacc[fc][r] * scale - mrun[r]);
        psum[r] += p;
        Ps[w * 16 + l16 * 4 + r][fc * 16 + l15] = f2bf(p);
      }
#pragma unroll
    for (int r = 0; r < 4; ++r) {
      psum[r] += __shfl_xor(psum[r], 1);
      psum[r] += __shfl_xor(psum[r], 2);
      psum[r] += __shfl_xor(psum[r], 4);
      psum[r] += __shfl_xor(psum[r], 8);
      lrun[r] = lrun[r] * alpha[r] + psum[r];
    }
#pragma unroll
    for (int fd = 0; fd < 3; ++fd)
#pragma unroll
      for (int r = 0; r < 4; ++r) accO[fd][r] *= alpha[r];
    __syncthreads();                           // order Ps writes vs vector reads
    // PV: O(16x48) += P(16x64) . V(64x48)
    short8v pa0 = *(const short8v*)&Ps[w * 16 + l15][l16 * 8];
    short8v pa1 = *(const short8v*)&Ps[w * 16 + l15][32 + l16 * 8];
#pragma unroll
    for (int fd = 0; fd < 3; ++fd) {
      short8v vb0 = *(const short8v*)&Vs[fd * 16 + l15][l16 * 8];
      short8v vb1 = *(const short8v*)&Vs[fd * 16 + l15][32 + l16 * 8];
      accO[fd] = __builtin_amdgcn_mfma_f32_16x16x32_bf16(pa0, vb0, accO[fd], 0, 0, 0);
      accO[fd] = __builtin_amdgcn_mfma_f32_16x16x32_bf16(pa1, vb1, accO[fd], 0, 0, 0);
    }
  }
#pragma unroll
  for (int fd = 0; fd < 3; ++fd)
#pragma unroll
    for (int r = 0; r < 4; ++r) {
      int qrow = qt * 64 + w * 16 + l16 * 4 + r;
      ao[base + (long)qrow * CDIM + fd * 16 + l15] = f2bf(accO[fd][r] / lrun[r]);
    }
}

// ---------------------------------------------------------------------------
extern "C" void kernel_launch(void* const* d_in, const int* in_sizes, int n_in,
                              void* d_out, int out_size, void* d_ws, size_t ws_size,
                              hipStream_t stream) {
  const float* x   = (const float*)d_in[0];
  const float* cw  = (const float*)d_in[1];
  const float* dwq = (const float*)d_in[2];
  const float* dwk = (const float*)d_in[3];
  const float* dwv = (const float*)d_in[4];
  const float* gq  = (const float*)d_in[5];
  const float* bq  = (const float*)d_in[6];
  const float* mq  = (const float*)d_in[7];
  const float* vq  = (const float*)d_in[8];
  const float* gk  = (const float*)d_in[9];
  const float* bk  = (const float*)d_in[10];
  const float* mk  = (const float*)d_in[11];
  const float* vk  = (const float*)d_in[12];
  const float* gv  = (const float*)d_in[13];
  const float* bv  = (const float*)d_in[14];
  const float* mv  = (const float*)d_in[15];
  const float* vv  = (const float*)d_in[16];
  const float* wq  = (const float*)d_in[17];
  const float* wk  = (const float*)d_in[18];
  const float* wv  = (const float*)d_in[19];
  const float* wo  = (const float*)d_in[20];
  const float* bo  = (const float*)d_in[21];
  float* out = (float*)d_out;

  char* wsb = (char*)d_ws;
  const size_t SLOTB = (size_t)NB * NPIX * CDIM * 4;   // 12,582,912 B
  float*  xr  = (float*)(wsb);                          // region 0 (fp32)
  ushort* q1  = (ushort*)(wsb);                         // region 0 lo (after xr dead)
  ushort* k1  = (ushort*)(wsb + SLOTB / 2);             // region 0 hi
  ushort* q0  = (ushort*)(wsb + SLOTB);                 // region 1 lo
  ushort* k0  = (ushort*)(wsb + SLOTB + SLOTB / 2);     // region 1 hi
  ushort* vtp = (ushort*)(wsb + SLOTB);                 // region 1 lo (after q0 dead)
  ushort* v0  = (ushort*)(wsb + 2 * SLOTB);             // region 2 lo
  ushort* v1  = (ushort*)(wsb + 2 * SLOTB + SLOTB / 2); // region 2 hi
  ushort* ao  = (ushort*)(wsb + 3 * SLOTB);             // region 3 lo
  ushort* wqb = (ushort*)(wsb + 3 * SLOTB + SLOTB / 2); // region 3 hi
  ushort* wkb = wqb + CDIM * CDIM;
  ushort* wvb = wkb + CDIM * CDIM;
  ushort* wob = wvb + CDIM * CDIM;

  wconv_k<<<dim3(144), 256, 0, stream>>>(wq, wk, wv, wo, wqb, wkb, wvb, wob);
  fft_filter_k<<<dim3(NB * CDIM), 256, 0, stream>>>(x, cw, xr, out);
  conv_bn_k<<<dim3(NB * CDIM), 256, 0, stream>>>(xr, dwq, dwk, dwv,
      gq, bq, mq, vq, gk, bk, mk, vk, gv, bv, mv, vv, q0, k0, v0);
  gemm_qkv_k<<<dim3(64, 6, 3), 256, 0, stream>>>(q0, k0, v0, wqb, wkb, wvb, q1, k1, v1);
  // q0/k0 dead now; vt overwrites region 1 lo
  vtrans_k<<<dim3(64, 16), 256, 0, stream>>>(v1, vtp);
  attn_mfma_k<<<dim3(64, 16), 256, 0, stream>>>(q1, k1, vtp, ao);
  gemm_out_k<<<dim3(64, 6), 256, 0, stream>>>(ao, wob, bo, out);
}

// Round 4
// 234.053 us; speedup vs baseline: 2.7598x; 1.1103x over previous
//
#include <hip/hip_runtime.h>
#include <cmath>

#define CDIM 384
#define NB 8
#define NPIX 1024

typedef __attribute__((ext_vector_type(8))) short short8v;
typedef __attribute__((ext_vector_type(4))) float float4v;

__device__ __forceinline__ ushort f2bf(float f) {
  union { float f; unsigned u; } v; v.f = f;
  unsigned r = (v.u + 0x7fffu + ((v.u >> 16) & 1u)) >> 16;
  return (ushort)r;
}

// ---------------------------------------------------------------------------
// Kernel 0: bf16 twiddle tables into ws.
// t=0: Tc[i][j]=cos(2pi ij/32)   t=1: Ts=sin   t=2: Tsn=-sin
// t=3: Uc[w][v]=c_v cos(2pi vw/32) (v<17 else 0), c_0=c_16=1 else 2
// t=4: Us[w][v]=-c_v sin(2pi vw/32) (v<17 else 0)
// ---------------------------------------------------------------------------
__global__ __launch_bounds__(256) void tables_k(ushort* __restrict__ tbl) {
  int i = blockIdx.x * 256 + threadIdx.x;
  if (i >= 5 * 1024) return;
  int t = i >> 10, j = i & 1023, r = j >> 5, cidx = j & 31;
  float ang = (float)((r * cidx) & 31) * 0.19634954084936207f;
  float val;
  if (t == 0) val = cosf(ang);
  else if (t == 1) val = sinf(ang);
  else if (t == 2) val = -sinf(ang);
  else {
    if (cidx > 16) val = 0.f;
    else {
      float cv = (cidx == 0 || cidx == 16) ? 1.f : 2.f;
      val = (t == 3) ? cv * cosf(ang) : -cv * sinf(ang);
    }
  }
  tbl[i] = f2bf(val);
}

// ---------------------------------------------------------------------------
// Kernel 1: spectral filter via MFMA.  one block per (b,c), 4 waves.
// buffers: 0=Tc 1=Ts 2=Tsn 3=Uc 4=Us 5=Xt/Xfr(f32) 6=Xfi(f32) 7=R1/Zr
//          8=I1/Zi 9=Ytr 10=Yti
// ---------------------------------------------------------------------------
__global__ __launch_bounds__(256) void fft_mfma_k(
    const float* __restrict__ x, const float* __restrict__ cw,
    const ushort* __restrict__ tbl, float* __restrict__ xr,
    float* __restrict__ out)
{
  const int b = blockIdx.x / CDIM, c = blockIdx.x % CDIM;
  const int tid = threadIdx.x;
  const int w = tid >> 6, lane = tid & 63;
  const int l15 = lane & 15, l16 = lane >> 4;
  __shared__ ushort B[11][32][40];

  for (int i = tid; i < 640; i += 256) {                 // tables -> LDS
    int t = i >> 7, j = i & 127, r = j >> 2, s = j & 3;
    *(uint4*)&B[t][r][s * 8] = *(const uint4*)&tbl[t * 1024 + r * 32 + s * 8];
  }
  for (int i = tid; i < 1024; i += 256)                  // input -> Xt[w][h]
    B[5][i & 31][i >> 5] = f2bf(x[(long)(b * 1024 + i) * CDIM + c]);
  __syncthreads();

  // stage1: R1[u,w] = sum_h Tc[u,h]*Xt[w,h];  I1 = sum_h Tsn[u,h]*Xt[w,h]
  for (int j = w; j < 8; j += 4) {
    int o = j & 1, ut = (j >> 1) & 1, wt = (j >> 2) & 1;
    short8v af = *(const short8v*)&B[o == 0 ? 0 : 2][ut * 16 + l15][l16 * 8];
    short8v bf = *(const short8v*)&B[5][wt * 16 + l15][l16 * 8];
    float4v acc = {0.f, 0.f, 0.f, 0.f};
    acc = __builtin_amdgcn_mfma_f32_16x16x32_bf16(af, bf, acc, 0, 0, 0);
    int dst = (o == 0) ? 7 : 8;
#pragma unroll
    for (int r = 0; r < 4; ++r)
      B[dst][ut * 16 + l16 * 4 + r][wt * 16 + l15] = f2bf(acc[r]);
  }
  __syncthreads();

  // stage2: Xfr[u,v] = R1.Tc + I1.Ts ; Xfi = I1.Tc + R1.Tsn  (fp32 raw store)
  for (int j = w; j < 8; j += 4) {
    int o = j & 1, ut = (j >> 1) & 1, vt = (j >> 2) & 1;
    short8v a1 = *(const short8v*)&B[o == 0 ? 7 : 8][ut * 16 + l15][l16 * 8];
    short8v b1 = *(const short8v*)&B[0][vt * 16 + l15][l16 * 8];
    short8v a2 = *(const short8v*)&B[o == 0 ? 8 : 7][ut * 16 + l15][l16 * 8];
    short8v b2 = *(const short8v*)&B[o == 0 ? 1 : 2][vt * 16 + l15][l16 * 8];
    float4v acc = {0.f, 0.f, 0.f, 0.f};
    acc = __builtin_amdgcn_mfma_f32_16x16x32_bf16(a1, b1, acc, 0, 0, 0);
    acc = __builtin_amdgcn_mfma_f32_16x16x32_bf16(a2, b2, acc, 0, 0, 0);
    int v = vt * 16 + l15;
    if (v < 17) {
      float* praw = (float*)&B[o == 0 ? 5 : 6][0][0];    // [32][20] f32 view
#pragma unroll
      for (int r = 0; r < 4; ++r)
        praw[(ut * 16 + l16 * 4 + r) * 20 + v] = acc[r];
    }
  }
  __syncthreads();

  // zero Ytr/Yti rows 17..31, then weight-multiply + transpose scatter
  for (int i = tid; i < 150; i += 256) {
    int buf = i / 75, j2 = i % 75, r2 = 17 + j2 / 5, s2 = j2 % 5;
    uint4 z = {0u, 0u, 0u, 0u};
    *(uint4*)&B[9 + buf][r2][s2 * 8] = z;
  }
  {
    const float* xfr = (const float*)&B[5][0][0];
    const float* xfi = (const float*)&B[6][0][0];
    for (int e = tid; e < 544; e += 256) {
      int u = e / 17, v = e - u * 17;
      float fr = xfr[u * 20 + v], fi = xfi[u * 20 + v];
      float2 wc = *(const float2*)&cw[((long)(c * 32 + u) * 17 + v) * 2];
      B[9][v][u]  = f2bf(fr * wc.x - fi * wc.y);
      B[10][v][u] = f2bf(fr * wc.y + fi * wc.x);
    }
  }
  __syncthreads();

  // stage3: Zr[h,v] = Tc(h).Ytr + Tsn(h).Yti ; Zi = Tc(h).Yti + Ts(h).Ytr
  for (int j = w; j < 8; j += 4) {
    int o = j & 1, ht = (j >> 1) & 1, vt = (j >> 2) & 1;
    short8v a1 = *(const short8v*)&B[0][ht * 16 + l15][l16 * 8];
    short8v b1 = *(const short8v*)&B[o == 0 ? 9 : 10][vt * 16 + l15][l16 * 8];
    short8v a2 = *(const short8v*)&B[o == 0 ? 2 : 1][ht * 16 + l15][l16 * 8];
    short8v b2 = *(const short8v*)&B[o == 0 ? 10 : 9][vt * 16 + l15][l16 * 8];
    float4v acc = {0.f, 0.f, 0.f, 0.f};
    acc = __builtin_amdgcn_mfma_f32_16x16x32_bf16(a1, b1, acc, 0, 0, 0);
    acc = __builtin_amdgcn_mfma_f32_16x16x32_bf16(a2, b2, acc, 0, 0, 0);
    int dst = (o == 0) ? 7 : 8;
#pragma unroll
    for (int r = 0; r < 4; ++r)
      B[dst][ht * 16 + l16 * 4 + r][vt * 16 + l15] = f2bf(acc[r]);
  }
  __syncthreads();

  // stage4: y[h,w] = (Zr.Uc^T + Zi.Us^T)/1024
  {
    int ht = w & 1, wt = (w >> 1) & 1;
    short8v a1 = *(const short8v*)&B[7][ht * 16 + l15][l16 * 8];
    short8v b1 = *(const short8v*)&B[3][wt * 16 + l15][l16 * 8];
    short8v a2 = *(const short8v*)&B[8][ht * 16 + l15][l16 * 8];
    short8v b2 = *(const short8v*)&B[4][wt * 16 + l15][l16 * 8];
    float4v acc = {0.f, 0.f, 0.f, 0.f};
    acc = __builtin_amdgcn_mfma_f32_16x16x32_bf16(a1, b1, acc, 0, 0, 0);
    acc = __builtin_amdgcn_mfma_f32_16x16x32_bf16(a2, b2, acc, 0, 0, 0);
#pragma unroll
    for (int r = 0; r < 4; ++r) {
      int hh = ht * 16 + l16 * 4 + r, ww = wt * 16 + l15;
      float y = acc[r] * (1.0f / 1024.0f);
      xr[((long)(b * CDIM) + c) * 1024 + hh * 32 + ww] = y;
      out[((long)(b * 1024) + hh * 32 + ww) * CDIM + c] = y;
    }
  }
}

// ---------------------------------------------------------------------------
// Kernel 2: depthwise 3x3 conv + BN -> bf16 outputs (B,N,C)
// ---------------------------------------------------------------------------
__global__ __launch_bounds__(256) void conv_bn_k(
    const float* __restrict__ xr,
    const float* __restrict__ dwq, const float* __restrict__ dwk, const float* __restrict__ dwv,
    const float* __restrict__ gq, const float* __restrict__ bq, const float* __restrict__ mq, const float* __restrict__ vq,
    const float* __restrict__ gk, const float* __restrict__ bk, const float* __restrict__ mk, const float* __restrict__ vk,
    const float* __restrict__ gv, const float* __restrict__ bv, const float* __restrict__ mv, const float* __restrict__ vv,
    ushort* __restrict__ q0, ushort* __restrict__ k0, ushort* __restrict__ v0)
{
  const int b = blockIdx.x / CDIM, c = blockIdx.x % CDIM;
  const int tid = threadIdx.x;
  __shared__ float xs[1024];
  for (int i = tid; i < 1024; i += 256)
    xs[i] = xr[(b * CDIM + c) * 1024 + i];
  float wq9[9], wk9[9], wv9[9];
#pragma unroll
  for (int t = 0; t < 9; ++t) {
    wq9[t] = dwq[c * 9 + t];
    wk9[t] = dwk[c * 9 + t];
    wv9[t] = dwv[c * 9 + t];
  }
  float scq = gq[c] * rsqrtf(vq[c] + 1e-5f); float shq = bq[c] - mq[c] * scq;
  float sck = gk[c] * rsqrtf(vk[c] + 1e-5f); float shk = bk[c] - mk[c] * sck;
  float scv = gv[c] * rsqrtf(vv[c] + 1e-5f); float shv = bv[c] - mv[c] * scv;
  __syncthreads();
  for (int i = tid; i < 1024; i += 256) {
    int h = i >> 5, w = i & 31;
    float aq = 0.f, ak = 0.f, av = 0.f;
#pragma unroll
    for (int dy = 0; dy < 3; ++dy) {
      int hh = h + dy - 1;
#pragma unroll
      for (int dx = 0; dx < 3; ++dx) {
        int ww = w + dx - 1;
        float xv = (hh >= 0 && hh < 32 && ww >= 0 && ww < 32) ? xs[(hh << 5) | ww] : 0.f;
        int t = dy * 3 + dx;
        aq += xv * wq9[t]; ak += xv * wk9[t]; av += xv * wv9[t];
      }
    }
    long o = (long)(b * 1024 + i) * CDIM + c;
    q0[o] = f2bf(aq * scq + shq);
    k0[o] = f2bf(ak * sck + shk);
    v0[o] = f2bf(av * scv + shv);
  }
}

// ---------------------------------------------------------------------------
// Kernel 2b: convert the 4 projection weights to bf16
// ---------------------------------------------------------------------------
__global__ __launch_bounds__(256) void wconv_k(
    const float* __restrict__ a, const float* __restrict__ b,
    const float* __restrict__ c, const float* __restrict__ d,
    ushort* __restrict__ oa, ushort* __restrict__ ob,
    ushort* __restrict__ oc, ushort* __restrict__ od)
{
  int i = blockIdx.x * 256 + threadIdx.x;
  if (i * 4 >= CDIM * CDIM) return;
  float4 va = *(const float4*)&a[i * 4];
  float4 vb = *(const float4*)&b[i * 4];
  float4 vc = *(const float4*)&c[i * 4];
  float4 vd = *(const float4*)&d[i * 4];
  ushort4 ra = { f2bf(va.x), f2bf(va.y), f2bf(va.z), f2bf(va.w) };
  ushort4 rb = { f2bf(vb.x), f2bf(vb.y), f2bf(vb.z), f2bf(vb.w) };
  ushort4 rc = { f2bf(vc.x), f2bf(vc.y), f2bf(vc.z), f2bf(vc.w) };
  ushort4 rd = { f2bf(vd.x), f2bf(vd.y), f2bf(vd.z), f2bf(vd.w) };
  *(ushort4*)&oa[i * 4] = ra;
  *(ushort4*)&ob[i * 4] = rb;
  *(ushort4*)&oc[i * 4] = rc;
  *(ushort4*)&od[i * 4] = rd;
}

// ---------------------------------------------------------------------------
// MFMA GEMM body  C[m,n'] = sum_k A[m,k] W[n',k]
// tile 128x64, BK=64, 4 waves (2x2), padded LDS (stride 72 bf16 = 144B).
// flags==0: bf16 store.  flags==1: fp32 RMW  out += acc + bias.
// ---------------------------------------------------------------------------
__device__ __forceinline__ void gemm_body(
    const ushort* __restrict__ A, const ushort* __restrict__ Wb,
    const float* __restrict__ bias, void* __restrict__ Cd, int flags,
    int bx, int by)
{
  __shared__ ushort As[128][72];
  __shared__ ushort Ws[64][72];
  const int tid = threadIdx.x;
  const int w = tid >> 6, lane = tid & 63;
  const int l15 = lane & 15, l16 = lane >> 4;
  const int wm = w >> 1, wn = w & 1;
  const int row0 = bx * 128, col0 = by * 64;
  float4v acc[4][2];
#pragma unroll
  for (int i = 0; i < 4; ++i)
#pragma unroll
    for (int j = 0; j < 2; ++j) acc[i][j] = (float4v){0.f, 0.f, 0.f, 0.f};
  for (int kt = 0; kt < CDIM; kt += 64) {
    if (kt) __syncthreads();
    for (int c = tid; c < 1024; c += 256) {
      int r = c >> 3, s = c & 7;
      *(uint4*)&As[r][s * 8] = *(const uint4*)&A[(long)(row0 + r) * CDIM + kt + s * 8];
    }
    for (int c = tid; c < 512; c += 256) {
      int r = c >> 3, s = c & 7;
      *(uint4*)&Ws[r][s * 8] = *(const uint4*)&Wb[(long)(col0 + r) * CDIM + kt + s * 8];
    }
    __syncthreads();
#pragma unroll
    for (int s = 0; s < 2; ++s) {
      short8v a[4], bfr[2];
#pragma unroll
      for (int i = 0; i < 4; ++i)
        a[i] = *(const short8v*)&As[wm * 64 + i * 16 + l15][s * 32 + l16 * 8];
#pragma unroll
      for (int j = 0; j < 2; ++j)
        bfr[j] = *(const short8v*)&Ws[wn * 32 + j * 16 + l15][s * 32 + l16 * 8];
#pragma unroll
      for (int i = 0; i < 4; ++i)
#pragma unroll
        for (int j = 0; j < 2; ++j)
          acc[i][j] = __builtin_amdgcn_mfma_f32_16x16x32_bf16(a[i], bfr[j], acc[i][j], 0, 0, 0);
    }
  }
#pragma unroll
  for (int i = 0; i < 4; ++i)
#pragma unroll
    for (int j = 0; j < 2; ++j) {
      int col = col0 + wn * 32 + j * 16 + l15;
      int rbase = row0 + wm * 64 + i * 16 + l16 * 4;
#pragma unroll
      for (int r = 0; r < 4; ++r) {
        long o = (long)(rbase + r) * CDIM + col;
        if (flags == 0) ((ushort*)Cd)[o] = f2bf(acc[i][j][r]);
        else            ((float*)Cd)[o] += acc[i][j][r] + bias[col];
      }
    }
}

// fused q/k/v projection GEMMs (blockIdx.z selects)
__global__ __launch_bounds__(256) void gemm_qkv_k(
    const ushort* __restrict__ q0, const ushort* __restrict__ k0, const ushort* __restrict__ v0,
    const ushort* __restrict__ wqb, const ushort* __restrict__ wkb, const ushort* __restrict__ wvb,
    ushort* __restrict__ q1, ushort* __restrict__ k1, ushort* __restrict__ v1)
{
  const int z = blockIdx.z;
  const ushort* A  = z == 0 ? q0  : z == 1 ? k0  : v0;
  const ushort* Wb = z == 0 ? wqb : z == 1 ? wkb : wvb;
  ushort*       C  = z == 0 ? q1  : z == 1 ? k1  : v1;
  gemm_body(A, Wb, nullptr, C, 0, blockIdx.x, blockIdx.y);
}

// final projection: out += A@wo^T + bo
__global__ __launch_bounds__(256) void gemm_out_k(
    const ushort* __restrict__ A, const ushort* __restrict__ Wb,
    const float* __restrict__ bias, float* __restrict__ Cd)
{
  gemm_body(A, Wb, bias, Cd, 1, blockIdx.x, blockIdx.y);
}

// ---------------------------------------------------------------------------
// Kernel 3b: V transpose  v1 (b,n,h*48+d) -> vt ((b*8+h)*48+d, n)
// ---------------------------------------------------------------------------
__global__ __launch_bounds__(256) void vtrans_k(
    const ushort* __restrict__ v1, ushort* __restrict__ vt)
{
  const int bh = blockIdx.x, b = bh >> 3, h = bh & 7;
  const int n0 = blockIdx.y * 64;
  const int tid = threadIdx.x;
  __shared__ unsigned Lu[64][49];
  for (int i = tid; i < 384; i += 256) {
    int r = i / 6, s = i - r * 6;
    uint4 p = *(const uint4*)&v1[(long)(b * 1024 + n0 + r) * CDIM + h * 48 + s * 8];
    unsigned d0 = s * 8;
    Lu[r][d0 + 0] = p.x & 0xffffu;        Lu[r][d0 + 1] = p.x >> 16;
    Lu[r][d0 + 2] = p.y & 0xffffu;        Lu[r][d0 + 3] = p.y >> 16;
    Lu[r][d0 + 4] = p.z & 0xffffu;        Lu[r][d0 + 5] = p.z >> 16;
    Lu[r][d0 + 6] = p.w & 0xffffu;        Lu[r][d0 + 7] = p.w >> 16;
  }
  __syncthreads();
  for (int i = tid; i < 384; i += 256) {
    int d = i >> 3, s = i & 7;
    uint4 o;
    o.x = Lu[s * 8 + 0][d] | (Lu[s * 8 + 1][d] << 16);
    o.y = Lu[s * 8 + 2][d] | (Lu[s * 8 + 3][d] << 16);
    o.z = Lu[s * 8 + 4][d] | (Lu[s * 8 + 5][d] << 16);
    o.w = Lu[s * 8 + 6][d] | (Lu[s * 8 + 7][d] << 16);
    *(uint4*)&vt[((long)bh * 48 + d) * NPIX + n0 + s * 8] = o;
  }
}

// ---------------------------------------------------------------------------
// Kernel 4: MFMA flash attention.  block = (b*8+h, 64-row Q tile), 4 waves.
// ---------------------------------------------------------------------------
__global__ __launch_bounds__(256) void attn_mfma_k(
    const ushort* __restrict__ q1, const ushort* __restrict__ k1,
    const ushort* __restrict__ vt, ushort* __restrict__ ao)
{
  const int bh = blockIdx.x, qt = blockIdx.y;
  const int b = bh >> 3, h = bh & 7;
  const int tid = threadIdx.x;
  const int w = tid >> 6, lane = tid & 63;
  const int l15 = lane & 15, l16 = lane >> 4;
  __shared__ ushort Qs[64][72], Ks[64][72], Ps[64][72];
  __shared__ ushort Vs[48][72];
  const float scale = 0.051031036307982884f;  // 384^-0.5
  const long base = (long)b * NPIX * CDIM + h * 48;
  const long vbase = (long)bh * 48 * NPIX;
  uint4 z4 = {0u, 0u, 0u, 0u};
  for (int i = tid; i < 128; i += 256) {       // zero-pad d=48..63
    int r = i >> 1, s = i & 1;
    *(uint4*)&Qs[r][48 + s * 8] = z4;
    *(uint4*)&Ks[r][48 + s * 8] = z4;
  }
  for (int i = tid; i < 384; i += 256) {       // stage Q once
    int r = i / 6, s = i - r * 6;
    *(uint4*)&Qs[r][s * 8] = *(const uint4*)&q1[base + (long)(qt * 64 + r) * CDIM + s * 8];
  }
  float mrun[4], lrun[4];
  float4v accO[3];
#pragma unroll
  for (int r = 0; r < 4; ++r) { mrun[r] = -1e30f; lrun[r] = 0.f; }
#pragma unroll
  for (int fd = 0; fd < 3; ++fd) accO[fd] = (float4v){0.f, 0.f, 0.f, 0.f};

  for (int kt = 0; kt < 16; ++kt) {
    if (kt) __syncthreads();
    for (int i = tid; i < 768; i += 256) {
      if (i < 384) {
        int r = i / 6, s = i - r * 6;
        *(uint4*)&Ks[r][s * 8] = *(const uint4*)&k1[base + (long)(kt * 64 + r) * CDIM + s * 8];
      } else {
        int j = i - 384, d = j >> 3, s = j & 7;
        *(uint4*)&Vs[d][s * 8] = *(const uint4*)&vt[vbase + (long)d * NPIX + kt * 64 + s * 8];
      }
    }
    __syncthreads();
    short8v qa0 = *(const short8v*)&Qs[w * 16 + l15][l16 * 8];
    short8v qa1 = *(const short8v*)&Qs[w * 16 + l15][32 + l16 * 8];
    float4v sacc[4];
#pragma unroll
    for (int fc = 0; fc < 4; ++fc) {
      sacc[fc] = (float4v){0.f, 0.f, 0.f, 0.f};
      short8v kb0 = *(const short8v*)&Ks[fc * 16 + l15][l16 * 8];
      short8v kb1 = *(const short8v*)&Ks[fc * 16 + l15][32 + l16 * 8];
      sacc[fc] = __builtin_amdgcn_mfma_f32_16x16x32_bf16(qa0, kb0, sacc[fc], 0, 0, 0);
      sacc[fc] = __builtin_amdgcn_mfma_f32_16x16x32_bf16(qa1, kb1, sacc[fc], 0, 0, 0);
    }
    float pmax[4] = {-1e30f, -1e30f, -1e30f, -1e30f};
#pragma unroll
    for (int fc = 0; fc < 4; ++fc)
#pragma unroll
      for (int r = 0; r < 4; ++r)
        pmax[r] = fmaxf(pmax[r], sacc[fc][r] * scale);
#pragma unroll
    for (int r = 0; r < 4; ++r) {
      pmax[r] = fmaxf(pmax[r], __shfl_xor(pmax[r], 1));
      pmax[r] = fmaxf(pmax[r], __shfl_xor(pmax[r], 2));
      pmax[r] = fmaxf(pmax[r], __shfl_xor(pmax[r], 4));
      pmax[r] = fmaxf(pmax[r], __shfl_xor(pmax[r], 8));
    }
    float alpha[4], psum[4];
#pragma unroll
    for (int r = 0; r < 4; ++r) {
      float mnew = fmaxf(mrun[r], pmax[r]);
      alpha[r] = __expf(mrun[r] - mnew);
      mrun[r] = mnew;
      psum[r] = 0.f;
    }
#pragma unroll
    for (int fc = 0; fc < 4; ++fc)
#pragma unroll
      for (int r = 0; r < 4; ++r) {
        float p = __expf(sacc[fc][r] * scale - mrun[r]);
        psum[r] += p;
        Ps[w * 16 + l16 * 4 + r][fc * 16 + l15] = f2bf(p);
      }
#pragma unroll
    for (int r = 0; r < 4; ++r) {
      psum[r] += __shfl_xor(psum[r], 1);
      psum[r] += __shfl_xor(psum[r], 2);
      psum[r] += __shfl_xor(psum[r], 4);
      psum[r] += __shfl_xor(psum[r], 8);
      lrun[r] = lrun[r] * alpha[r] + psum[r];
    }
#pragma unroll
    for (int fd = 0; fd < 3; ++fd)
#pragma unroll
      for (int r = 0; r < 4; ++r) accO[fd][r] *= alpha[r];
    __syncthreads();
    short8v pa0 = *(const short8v*)&Ps[w * 16 + l15][l16 * 8];
    short8v pa1 = *(const short8v*)&Ps[w * 16 + l15][32 + l16 * 8];
#pragma unroll
    for (int fd = 0; fd < 3; ++fd) {
      short8v vb0 = *(const short8v*)&Vs[fd * 16 + l15][l16 * 8];
      short8v vb1 = *(const short8v*)&Vs[fd * 16 + l15][32 + l16 * 8];
      accO[fd] = __builtin_amdgcn_mfma_f32_16x16x32_bf16(pa0, vb0, accO[fd], 0, 0, 0);
      accO[fd] = __builtin_amdgcn_mfma_f32_16x16x32_bf16(pa1, vb1, accO[fd], 0, 0, 0);
    }
  }
#pragma unroll
  for (int fd = 0; fd < 3; ++fd)
#pragma unroll
    for (int r = 0; r < 4; ++r) {
      int qrow = qt * 64 + w * 16 + l16 * 4 + r;
      ao[base + (long)qrow * CDIM + fd * 16 + l15] = f2bf(accO[fd][r] / lrun[r]);
    }
}

// ---------------------------------------------------------------------------
extern "C" void kernel_launch(void* const* d_in, const int* in_sizes, int n_in,
                              void* d_out, int out_size, void* d_ws, size_t ws_size,
                              hipStream_t stream) {
  const float* x   = (const float*)d_in[0];
  const float* cw  = (const float*)d_in[1];
  const float* dwq = (const float*)d_in[2];
  const float* dwk = (const float*)d_in[3];
  const float* dwv = (const float*)d_in[4];
  const float* gq  = (const float*)d_in[5];
  const float* bq  = (const float*)d_in[6];
  const float* mq  = (const float*)d_in[7];
  const float* vq  = (const float*)d_in[8];
  const float* gk  = (const float*)d_in[9];
  const float* bk  = (const float*)d_in[10];
  const float* mk  = (const float*)d_in[11];
  const float* vk  = (const float*)d_in[12];
  const float* gv  = (const float*)d_in[13];
  const float* bv  = (const float*)d_in[14];
  const float* mv  = (const float*)d_in[15];
  const float* vv  = (const float*)d_in[16];
  const float* wq  = (const float*)d_in[17];
  const float* wk  = (const float*)d_in[18];
  const float* wv  = (const float*)d_in[19];
  const float* wo  = (const float*)d_in[20];
  const float* bo  = (const float*)d_in[21];
  float* out = (float*)d_out;

  char* wsb = (char*)d_ws;
  const size_t SLOTB = (size_t)NB * NPIX * CDIM * 4;   // 12,582,912 B
  float*  xr  = (float*)(wsb);                          // region 0 (fp32)
  ushort* q1  = (ushort*)(wsb);                         // region 0 lo (after xr dead)
  ushort* k1  = (ushort*)(wsb + SLOTB / 2);             // region 0 hi
  ushort* q0  = (ushort*)(wsb + SLOTB);                 // region 1 lo
  ushort* k0  = (ushort*)(wsb + SLOTB + SLOTB / 2);     // region 1 hi
  ushort* vtp = (ushort*)(wsb + SLOTB);                 // region 1 lo (after q0 dead)
  ushort* v0  = (ushort*)(wsb + 2 * SLOTB);             // region 2 lo
  ushort* v1  = (ushort*)(wsb + 2 * SLOTB + SLOTB / 2); // region 2 hi
  ushort* ao  = (ushort*)(wsb + 3 * SLOTB);             // region 3 lo
  ushort* wqb = (ushort*)(wsb + 3 * SLOTB + SLOTB / 2); // region 3 hi
  ushort* wkb = wqb + CDIM * CDIM;
  ushort* wvb = wkb + CDIM * CDIM;
  ushort* wob = wvb + CDIM * CDIM;
  ushort* tbl = wob + CDIM * CDIM;                      // 5*1024 ushorts

  tables_k<<<dim3(20), 256, 0, stream>>>(tbl);
  wconv_k<<<dim3(144), 256, 0, stream>>>(wq, wk, wv, wo, wqb, wkb, wvb, wob);
  fft_mfma_k<<<dim3(NB * CDIM), 256, 0, stream>>>(x, cw, tbl, xr, out);
  conv_bn_k<<<dim3(NB * CDIM), 256, 0, stream>>>(xr, dwq, dwk, dwv,
      gq, bq, mq, vq, gk, bk, mk, vk, gv, bv, mv, vv, q0, k0, v0);
  gemm_qkv_k<<<dim3(64, 6, 3), 256, 0, stream>>>(q0, k0, v0, wqb, wkb, wvb, q1, k1, v1);
  vtrans_k<<<dim3(64, 16), 256, 0, stream>>>(v1, vtp);
  attn_mfma_k<<<dim3(64, 16), 256, 0, stream>>>(q1, k1, vtp, ao);
  gemm_out_k<<<dim3(64, 6), 256, 0, stream>>>(ao, wob, bo, out);
}